// Round 3
// baseline (172.644 us; speedup 1.0000x reference)
//
#include <hip/hip_runtime.h>
#include <cstdint>

#define S_CNT 10000
#define R_CNT 10000
#define NBUCKET 50
#define CAP 21504                 // slots per t-bucket: E=20000, sigma~140 -> +10.7 sigma
#define CURS 16                   // cursor padding stride in ints (64B apart)
#define NSLOT (NBUCKET * CAP)     // 1,075,200
#define CUR_INTS (64 * CURS)      // 1024 ints of cursor space
#define IDX_OFF_INTS CUR_INTS
#define PACKED_OFF_BYTES (4096 + 4 * NSLOT)          // 16B-aligned
#define WS_NEED ((size_t)PACKED_OFF_BYTES + 16ull * NSLOT)

// ---- pass Z: zero the bucket cursors ----
__global__ __launch_bounds__(256) void zero_kernel(int* __restrict__ ws) {
    ws[blockIdx.x * 256 + threadIdx.x] = 0;   // grid = 4 -> 1024 ints
}

// ---- pass C: single-pass bin-by-t scatter into workspace ----
__global__ __launch_bounds__(256) void bin_kernel(
    const int* __restrict__ X, int n, int* __restrict__ ws,
    const float* __restrict__ se, const float* __restrict__ re,
    const float* __restrict__ pe, float* __restrict__ out)
{
    __shared__ int lhist[NBUCKET], lbase[NBUCKET], lcur[NBUCKET];
    int* cursors = ws;
    int* idxArr  = ws + IDX_OFF_INTS;
    int4* packed = reinterpret_cast<int4*>(reinterpret_cast<char*>(ws) + PACKED_OFF_BYTES);

    const int tid = threadIdx.x;
    const long long base = (long long)blockIdx.x * 1024;
    if (tid < NBUCKET) lhist[tid] = 0;
    __syncthreads();

    int4 xs[4];
    #pragma unroll
    for (int it = 0; it < 4; ++it) {
        const long long i = base + it * 256 + tid;
        if (i < n) {
            xs[it] = *reinterpret_cast<const int4*>(X + 4 * i);
            atomicAdd(&lhist[xs[it].w], 1);
        } else {
            xs[it].w = -1;
        }
    }
    __syncthreads();
    if (tid < NBUCKET) {
        const int c = lhist[tid];
        lbase[tid] = c ? atomicAdd(&cursors[tid * CURS], c) : 0;
        lcur[tid] = 0;
    }
    __syncthreads();
    #pragma unroll
    for (int it = 0; it < 4; ++it) {
        const int t = xs[it].w;
        if (t < 0) continue;
        const long long i = base + it * 256 + tid;
        const int rank = lbase[t] + atomicAdd(&lcur[t], 1);
        if (rank < CAP) {
            const int gidx = t * CAP + rank;
            packed[gidx] = xs[it];
            idxArr[gidx] = (int)i;
        } else {
            // statistically unreachable overflow: compute this sample directly
            const long long st = (long long)xs[it].x + (long long)t * S_CNT;
            const long long rt = (long long)xs[it].y + (long long)t * R_CNT;
            const long long p  = xs[it].z;
            float acc = 0.f;
            for (int k = 0; k < 64; ++k)
                acc += se[st * 64 + k] * pe[p * 128 + k]
                     + re[rt * 64 + k] * pe[p * 128 + 64 + k];
            out[i] = 1.0f / (1.0f + __expf(-acc));
        }
    }
}

// ---- pass D: bucket-ordered gather + dot + sigmoid (16 lanes per sample) ----
__global__ __launch_bounds__(256) void dot_kernel(
    const int* __restrict__ ws,
    const float* __restrict__ s_embeds,
    const float* __restrict__ r_embeds,
    const float* __restrict__ p_embeds,
    float* __restrict__ out)
{
    const int g = threadIdx.x >> 4;
    const int l = threadIdx.x & 15;
    const int j = blockIdx.x * 16 + g;           // slot index
    if (j >= NSLOT) return;
    const unsigned bucket = (unsigned)j / CAP;
    const unsigned rank   = (unsigned)j - bucket * CAP;
    const int cnt = ws[bucket * CURS];
    if (rank >= (unsigned)cnt) return;           // gap slot

    const int4 pk = reinterpret_cast<const int4*>(
        reinterpret_cast<const char*>(ws) + PACKED_OFF_BYTES)[j];
    const int i = ws[IDX_OFF_INTS + j];

    const long long st = (long long)pk.x + (long long)pk.w * S_CNT;
    const long long rt = (long long)pk.y + (long long)pk.w * R_CNT;
    const long long p  = pk.z;

    const float4 se = *reinterpret_cast<const float4*>(s_embeds + st * 64 + l * 4);
    const float4 re = *reinterpret_cast<const float4*>(r_embeds + rt * 64 + l * 4);
    const float4 pl = *reinterpret_cast<const float4*>(p_embeds + p * 128 + l * 4);
    const float4 ph = *reinterpret_cast<const float4*>(p_embeds + p * 128 + 64 + l * 4);

    float acc = se.x * pl.x + se.y * pl.y + se.z * pl.z + se.w * pl.w
              + re.x * ph.x + re.y * ph.y + re.z * ph.z + re.w * ph.w;

    acc += __shfl_xor(acc, 1, 64);
    acc += __shfl_xor(acc, 2, 64);
    acc += __shfl_xor(acc, 4, 64);
    acc += __shfl_xor(acc, 8, 64);

    if (l == 0) out[i] = 1.0f / (1.0f + __expf(-acc));
}

// ---- fallback: direct kernel (used only if workspace is too small) ----
__global__ __launch_bounds__(256) void direct_kernel(
    const int* __restrict__ X,
    const float* __restrict__ s_embeds,
    const float* __restrict__ r_embeds,
    const float* __restrict__ p_embeds,
    float* __restrict__ out, int n)
{
    const int g = threadIdx.x >> 4;
    const int l = threadIdx.x & 15;
    const int i = blockIdx.x * 16 + g;
    if (i >= n) return;
    const int4 xi = *reinterpret_cast<const int4*>(X + 4ll * i);
    const long long st = (long long)xi.x + (long long)xi.w * S_CNT;
    const long long rt = (long long)xi.y + (long long)xi.w * R_CNT;
    const long long p  = xi.z;
    const float4 se = *reinterpret_cast<const float4*>(s_embeds + st * 64 + l * 4);
    const float4 re = *reinterpret_cast<const float4*>(r_embeds + rt * 64 + l * 4);
    const float4 pl = *reinterpret_cast<const float4*>(p_embeds + p * 128 + l * 4);
    const float4 ph = *reinterpret_cast<const float4*>(p_embeds + p * 128 + 64 + l * 4);
    float acc = se.x * pl.x + se.y * pl.y + se.z * pl.z + se.w * pl.w
              + re.x * ph.x + re.y * ph.y + re.z * ph.z + re.w * ph.w;
    acc += __shfl_xor(acc, 1, 64);
    acc += __shfl_xor(acc, 2, 64);
    acc += __shfl_xor(acc, 4, 64);
    acc += __shfl_xor(acc, 8, 64);
    if (l == 0) out[i] = 1.0f / (1.0f + __expf(-acc));
}

extern "C" void kernel_launch(void* const* d_in, const int* in_sizes, int n_in,
                              void* d_out, int out_size, void* d_ws, size_t ws_size,
                              hipStream_t stream) {
    const int*   X        = (const int*)d_in[0];
    const float* s_embeds = (const float*)d_in[1];
    const float* r_embeds = (const float*)d_in[2];
    const float* p_embeds = (const float*)d_in[3];
    float* out = (float*)d_out;
    const int n = in_sizes[0] / 4;

    if (ws_size < WS_NEED) {
        direct_kernel<<<(n + 15) / 16, 256, 0, stream>>>(
            X, s_embeds, r_embeds, p_embeds, out, n);
        return;
    }

    int* ws = (int*)d_ws;
    zero_kernel<<<CUR_INTS / 256, 256, 0, stream>>>(ws);
    bin_kernel<<<(n + 1023) / 1024, 256, 0, stream>>>(
        X, n, ws, s_embeds, r_embeds, p_embeds, out);
    dot_kernel<<<(NSLOT + 15) / 16, 256, 0, stream>>>(
        ws, s_embeds, r_embeds, p_embeds, out);
}